// Round 3
// baseline (350.271 us; speedup 1.0000x reference)
//
#include <hip/hip_runtime.h>
#include <hip/hip_bf16.h>
#include <math.h>

#define NN 2048      // nodes
#define NE 4096      // edges
#define D 128
#define NODE_K 1024
#define EDGE_K 2048
#define CAP 64       // per-node incident-edge list capacity (mean degree 4)

typedef const __hip_bfloat16* bfp;
__device__ __forceinline__ float b2f(__hip_bfloat16 x) { return __bfloat162float(x); }

// prefix offsets (element counts) of the 14 float tensors in the fp32 region
__device__ __constant__ const int kPrefix[15] = {
  0, 262144, 786432, 786560, 786688, 803072, 819456, 835840,
  852224, 868608, 884992, 901376, 901504, 903552, 903568};
#define TOTAL_F 903568

struct CvtSrc { const void* p[14]; };

// ---------- dtype detector + deg zeroing ----------
// Reads first 4096 16-bit halves of node_features as bf16. True bf16 N(0,1)
// data: ~0 weird values. fp32-underlying: even halves are fp32 mantissa bits
// -> random exponent -> ~40% weird. flag=1 means inputs are fp32.
__global__ void detect_kernel(const unsigned short* __restrict__ nf_raw,
                              int* __restrict__ flag, int* __restrict__ deg) {
  int t = threadIdx.x;  // 256 threads, 1 block
  int weird = 0;
  for (int i = t; i < 4096; i += 256) {
    unsigned int bits = ((unsigned int)nf_raw[i]) << 16;
    float x = __uint_as_float(bits);
    float ax = fabsf(x);
    if (!(ax <= 1e3f) || (x != 0.f && ax < 1e-12f)) weird++;  // nan/inf/huge/denorm
  }
  #pragma unroll
  for (int m = 32; m >= 1; m >>= 1) weird += __shfl_xor(weird, m);
  __shared__ int s[4];
  if ((t & 63) == 0) s[t >> 6] = weird;
  __syncthreads();
  if (t == 0) flag[0] = (s[0] + s[1] + s[2] + s[3] > 200) ? 1 : 0;
  for (int i = t; i < NN; i += 256) deg[i] = 0;
}

// ---------- normalize all float inputs into one fp32 region ----------
__global__ void convert_kernel(CvtSrc srcs, float* __restrict__ dst,
                               const int* __restrict__ flag) {
  int f = flag[0];
  for (int i = blockIdx.x * blockDim.x + threadIdx.x; i < TOTAL_F;
       i += gridDim.x * blockDim.x) {
    int tt = 0;
    while (i >= kPrefix[tt + 1]) ++tt;
    int off = i - kPrefix[tt];
    float v;
    if (f) v = ((const float*)srcs.p[tt])[off];
    else   v = b2f(((bfp)srcs.p[tt])[off]);
    dst[i] = v;
  }
}

// ---------- router scores: one wave per row, fp64 accumulate (rank stability) ----
__global__ void scores_kernel(const float* __restrict__ nf, const float* __restrict__ ef,
                              const float* __restrict__ wrn, const float* __restrict__ wre,
                              float* __restrict__ ns, float* __restrict__ es) {
  int gid = blockIdx.x * blockDim.x + threadIdx.x;
  int wid = gid >> 6, lane = gid & 63;
  if (wid >= NN + NE) return;
  const float* row; const float* w; float* out;
  if (wid < NN) { row = nf + (size_t)wid * D;        w = wrn; out = ns + wid; }
  else          { int r = wid - NN; row = ef + (size_t)r * D; w = wre; out = es + r; }
  double p = (double)row[lane] * (double)w[lane]
           + (double)row[lane + 64] * (double)w[lane + 64];
  #pragma unroll
  for (int m = 32; m >= 1; m >>= 1) p += __shfl_xor(p, m);
  if (lane == 0) *out = (float)p;
}

// ---------- exact top-k via stable rank (matches lax.top_k tie semantics) ----------
__global__ void node_mask_kernel(const float* __restrict__ ns, int* __restrict__ node_mask) {
  __shared__ float s[NN];
  for (int i = threadIdx.x; i < NN; i += blockDim.x) s[i] = ns[i];
  __syncthreads();
  int i = blockIdx.x * blockDim.x + threadIdx.x;
  float si = s[i];
  int rank = 0;
  for (int j = 0; j < NN; ++j) {
    float sj = s[j];
    rank += (sj > si) || (sj == si && j < i);
  }
  node_mask[i] = (rank < NODE_K) ? 1 : 0;
}

__global__ void edge_mask_kernel(const float* __restrict__ es, const int* __restrict__ src,
                                 const int* __restrict__ dst, const int* __restrict__ node_mask,
                                 int* __restrict__ edge_mask) {
  __shared__ float s[NE];
  for (int i = threadIdx.x; i < NE; i += blockDim.x) s[i] = es[i];
  __syncthreads();
  int i = blockIdx.x * blockDim.x + threadIdx.x;
  float si = s[i];
  int rank = 0;
  for (int j = 0; j < NE; ++j) {
    float sj = s[j];
    rank += (sj > si) || (sj == si && j < i);
  }
  edge_mask[i] = ((rank < EDGE_K) && node_mask[src[i]] && node_mask[dst[i]]) ? 1 : 0;
}

// ---------- incident-edge lists ----------
__global__ void build_lists_kernel(const int* __restrict__ src, const int* __restrict__ dst,
                                   int* __restrict__ deg, int* __restrict__ lists) {
  int e = blockIdx.x * blockDim.x + threadIdx.x;
  if (e >= NE) return;
  int s = src[e], d = dst[e];
  int p = atomicAdd(&deg[s], 1);
  if (p >= 0 && p < CAP) lists[s * CAP + p] = e;
  if (d != s) {
    p = atomicAdd(&deg[d], 1);
    if (p >= 0 && p < CAP) lists[d * CAP + p] = e;
  }
}

// ---------- prep: masked edge feats + endpoint node-feature sum ----------
__global__ void prep_kernel(const float* __restrict__ ef, const float* __restrict__ nf,
                            const int* __restrict__ src, const int* __restrict__ dst,
                            const int* __restrict__ edge_mask,
                            float* __restrict__ efm, float* __restrict__ nsum) {
  int idx = blockIdx.x * blockDim.x + threadIdx.x;  // NE*D exactly
  int e = idx >> 7, c = idx & 127;
  float m = edge_mask[e] ? 1.f : 0.f;
  efm[idx] = m * ef[idx];
  nsum[idx] = nf[src[e] * D + c] + nf[dst[e] * D + c];
}

// ---------- C[M,128] = act(A[M,128] @ W[128,128] (+Cin) (+bias)), fp32 W ----------
#define ROWS 16
__global__ __launch_bounds__(256) void gemm_kernel(
    const float* __restrict__ A, const float* __restrict__ W,
    const float* __restrict__ Cin, const float* __restrict__ bias,
    int act, float* __restrict__ C) {
  __shared__ float Wl[64 * D];   // 32 KB (half of W at a time)
  __shared__ float Al[ROWS * D]; // 8 KB
  int t = threadIdx.x;
  int row0 = blockIdx.x * ROWS;
  for (int i = t; i < ROWS * D; i += 256) Al[i] = A[row0 * D + i];
  int j = t & 127, rg = t >> 7;  // rg in {0,1}: 8 rows per thread
  float acc[8] = {0.f, 0.f, 0.f, 0.f, 0.f, 0.f, 0.f, 0.f};
  for (int half = 0; half < 2; ++half) {
    __syncthreads();
    for (int i = t; i < 64 * D; i += 256) Wl[i] = W[half * 64 * D + i];
    __syncthreads();
    for (int k = 0; k < 64; ++k) {
      float w = Wl[k * D + j];
      #pragma unroll
      for (int r = 0; r < 8; ++r) acc[r] += Al[(rg * 8 + r) * D + (half * 64 + k)] * w;
    }
  }
  #pragma unroll
  for (int r = 0; r < 8; ++r) {
    int row = row0 + rg * 8 + r;
    float res = acc[r];
    if (Cin) res += Cin[row * D + j];
    if (bias) res += bias[j];
    if (act == 1) {  // jax.nn.gelu default (tanh approximation)
      float u = res;
      float inner = 0.7978845608028654f * (u + 0.044715f * u * u * u);
      res = 0.5f * u * (1.f + tanhf(inner));
    }
    C[row * D + j] = res;
  }
}

// ---------- sparse edge attention: one block (128 thr) per query edge ----------
// masked full-softmax entries contribute exp(-1e9-m)==0 in fp32, so iterating
// the incident-edge union is exact.
__global__ void attn_kernel(const float* __restrict__ q, const float* __restrict__ k,
                            const float* __restrict__ v, const int* __restrict__ src,
                            const int* __restrict__ dst, const int* __restrict__ deg,
                            const int* __restrict__ lists, float* __restrict__ ao) {
  int e = blockIdx.x;
  int j = threadIdx.x;  // head = j/32, d = j%32 (shfl_xor<32 stays in-head)
  float qj = q[e * D + j];
  int sn = src[e], dn = dst[e];
  float m = -1e30f, l = 0.f, acc = 0.f;
  const float scale = 0.17677669529663687f;  // 1/sqrt(32)
  int degA = max(0, min(deg[sn], CAP));
  for (int i = 0; i < degA; ++i) {
    int f = lists[sn * CAP + i];
    float p = qj * k[f * D + j];
    p += __shfl_xor(p, 16); p += __shfl_xor(p, 8); p += __shfl_xor(p, 4);
    p += __shfl_xor(p, 2);  p += __shfl_xor(p, 1);
    float s = p * scale;
    float vj = v[f * D + j];
    float mn = fmaxf(m, s);
    float corr = expf(m - mn);
    float w = expf(s - mn);
    l = l * corr + w;
    acc = acc * corr + w * vj;
    m = mn;
  }
  if (dn != sn) {
    int degB = max(0, min(deg[dn], CAP));
    for (int i = 0; i < degB; ++i) {
      int f = lists[dn * CAP + i];
      if (src[f] == sn || dst[f] == sn) continue;  // already in list A
      float p = qj * k[f * D + j];
      p += __shfl_xor(p, 16); p += __shfl_xor(p, 8); p += __shfl_xor(p, 4);
      p += __shfl_xor(p, 2);  p += __shfl_xor(p, 1);
      float s = p * scale;
      float vj = v[f * D + j];
      float mn = fmaxf(m, s);
      float corr = expf(m - mn);
      float w = expf(s - mn);
      l = l * corr + w;
      acc = acc * corr + w * vj;
      m = mn;
    }
  }
  ao[e * D + j] = acc / fmaxf(l, 1e-37f);  // l >= 1 normally (f==e term)
}

// ---------- logits: X[E,128] @ W2[128,16] + b2 -> out (dtype per flag) ----------
__global__ __launch_bounds__(256) void logits_kernel(
    const float* __restrict__ X, const float* __restrict__ W2,
    const float* __restrict__ b2v, const int* __restrict__ flag,
    void* __restrict__ out) {
  __shared__ float Xl[16 * D];
  __shared__ float W2l[D * 16];
  int t = threadIdx.x;
  int row0 = blockIdx.x * 16;
  for (int i = t; i < 16 * D; i += 256) Xl[i] = X[row0 * D + i];
  for (int i = t; i < D * 16; i += 256) W2l[i] = W2[i];
  __syncthreads();
  int j = t & 15, r = t >> 4;
  float acc = 0.f;
  for (int kk = 0; kk < D; ++kk) acc += Xl[r * D + kk] * W2l[kk * 16 + j];
  acc += b2v[j];
  int idx = (row0 + r) * 16 + j;
  if (flag[0]) ((float*)out)[idx] = acc;
  else ((__hip_bfloat16*)out)[idx] = __float2bfloat16(acc);
}

extern "C" void kernel_launch(void* const* d_in, const int* in_sizes, int n_in,
                              void* d_out, int out_size, void* d_ws, size_t ws_size,
                              hipStream_t stream) {
  const int* eidx = (const int*)d_in[2];
  const int* src = eidx;
  const int* dst = eidx + NE;

  // workspace carve
  size_t off = 0;
  char* base = (char*)d_ws;
  auto alloc = [&](size_t nbytes) -> void* {
    void* p = base + off;
    off += (nbytes + 255) & ~(size_t)255;
    return p;
  };
  int* flag        = (int*)alloc(256);
  float* F         = (float*)alloc((size_t)TOTAL_F * sizeof(float));  // fp32 inputs
  float* ns        = (float*)alloc(NN * sizeof(float));
  float* es        = (float*)alloc(NE * sizeof(float));
  int* node_mask   = (int*)alloc(NN * sizeof(int));
  int* edge_mask   = (int*)alloc(NE * sizeof(int));
  int* deg         = (int*)alloc(NN * sizeof(int));
  int* lists       = (int*)alloc((size_t)NN * CAP * sizeof(int));
  float* efm       = (float*)alloc((size_t)NE * D * sizeof(float));
  float* nsum      = (float*)alloc((size_t)NE * D * sizeof(float));
  float* hbuf      = (float*)alloc((size_t)NE * D * sizeof(float));
  float* qb        = (float*)alloc((size_t)NE * D * sizeof(float));
  float* kb        = (float*)alloc((size_t)NE * D * sizeof(float));
  float* vb        = (float*)alloc((size_t)NE * D * sizeof(float));
  float* ao        = (float*)alloc((size_t)NE * D * sizeof(float));
  float* ob = efm;   // reuse (dead after h)
  float* xb = nsum;  // reuse (dead after h)

  // pointers into the converted fp32 region (offsets = kPrefix)
  const float* NF  = F + 0;
  const float* EF  = F + 262144;
  const float* WRN = F + 786432;
  const float* WRE = F + 786560;
  const float* WE  = F + 786688;
  const float* WNp = F + 803072;
  const float* WQ  = F + 819456;
  const float* WK  = F + 835840;
  const float* WV  = F + 852224;
  const float* WO  = F + 868608;
  const float* W1  = F + 884992;
  const float* B1  = F + 901376;
  const float* W2P = F + 901504;
  const float* B2P = F + 903552;

  CvtSrc srcs;
  srcs.p[0]  = d_in[0];   // node_features
  srcs.p[1]  = d_in[1];   // edge_features
  srcs.p[2]  = d_in[3];   // w_router_n
  srcs.p[3]  = d_in[4];   // w_router_e
  srcs.p[4]  = d_in[5];   // w_e
  srcs.p[5]  = d_in[6];   // w_n
  srcs.p[6]  = d_in[7];   // w_q
  srcs.p[7]  = d_in[8];   // w_k
  srcs.p[8]  = d_in[9];   // w_v
  srcs.p[9]  = d_in[10];  // w_o
  srcs.p[10] = d_in[11];  // w1
  srcs.p[11] = d_in[12];  // b1
  srcs.p[12] = d_in[13];  // w2
  srcs.p[13] = d_in[14];  // b2

  // 0. dtype detect + zero deg
  detect_kernel<<<1, 256, 0, stream>>>((const unsigned short*)d_in[0], flag, deg);
  // 1. normalize all float inputs to fp32
  convert_kernel<<<1024, 256, 0, stream>>>(srcs, F, flag);
  // 2. router scores
  scores_kernel<<<(NN + NE) * 64 / 256, 256, 0, stream>>>(NF, EF, WRN, WRE, ns, es);
  // 3. exact top-k masks
  node_mask_kernel<<<NN / 256, 256, 0, stream>>>(ns, node_mask);
  edge_mask_kernel<<<NE / 256, 256, 0, stream>>>(es, src, dst, node_mask, edge_mask);
  // 4. incident-edge lists
  build_lists_kernel<<<NE / 256, 256, 0, stream>>>(src, dst, deg, lists);
  // 5. masked edge feats + node sums
  prep_kernel<<<(NE * D) / 256, 256, 0, stream>>>(EF, NF, src, dst, edge_mask, efm, nsum);
  // 6. h = efm@w_e + nsum@w_n
  gemm_kernel<<<NE / ROWS, 256, 0, stream>>>(efm, WE, nullptr, nullptr, 0, hbuf);
  gemm_kernel<<<NE / ROWS, 256, 0, stream>>>(nsum, WNp, hbuf, nullptr, 0, hbuf);
  // 7. q,k,v projections
  gemm_kernel<<<NE / ROWS, 256, 0, stream>>>(hbuf, WQ, nullptr, nullptr, 0, qb);
  gemm_kernel<<<NE / ROWS, 256, 0, stream>>>(hbuf, WK, nullptr, nullptr, 0, kb);
  gemm_kernel<<<NE / ROWS, 256, 0, stream>>>(hbuf, WV, nullptr, nullptr, 0, vb);
  // 8. sparse edge attention
  attn_kernel<<<NE, 128, 0, stream>>>(qb, kb, vb, src, dst, deg, lists, ao);
  // 9. output projection + MLP + logits
  gemm_kernel<<<NE / ROWS, 256, 0, stream>>>(ao, WO, nullptr, nullptr, 0, ob);
  gemm_kernel<<<NE / ROWS, 256, 0, stream>>>(ob, W1, nullptr, B1, 1, xb);
  logits_kernel<<<NE / 16, 256, 0, stream>>>(xb, W2P, B2P, flag, d_out);
}

// Round 4
// 185.918 us; speedup vs baseline: 1.8840x; 1.8840x over previous
//
#include <hip/hip_runtime.h>
#include <hip/hip_bf16.h>
#include <math.h>

#define NN 2048      // nodes
#define NE 4096      // edges
#define D 128
#define NODE_K 1024
#define EDGE_K 2048
#define CAP 64       // per-node incident-edge list capacity (mean degree 4)

typedef const __hip_bfloat16* bfp;
__device__ __forceinline__ float b2f(__hip_bfloat16 x) { return __bfloat162float(x); }

// prefix offsets (element counts) of the 14 float tensors in the fp32 region
__device__ __constant__ const int kPrefix[15] = {
  0, 262144, 786432, 786560, 786688, 803072, 819456, 835840,
  852224, 868608, 884992, 901376, 901504, 903552, 903568};
#define TOTAL_F 903568

struct CvtSrc { const void* p[14]; };

// ---------- dtype detector + deg zeroing ----------
__global__ void detect_kernel(const unsigned short* __restrict__ nf_raw,
                              int* __restrict__ flag, int* __restrict__ deg) {
  int t = threadIdx.x;  // 256 threads, 1 block
  int weird = 0;
  for (int i = t; i < 4096; i += 256) {
    unsigned int bits = ((unsigned int)nf_raw[i]) << 16;
    float x = __uint_as_float(bits);
    float ax = fabsf(x);
    if (!(ax <= 1e3f) || (x != 0.f && ax < 1e-12f)) weird++;  // nan/inf/huge/denorm
  }
  #pragma unroll
  for (int m = 32; m >= 1; m >>= 1) weird += __shfl_xor(weird, m);
  __shared__ int s[4];
  if ((t & 63) == 0) s[t >> 6] = weird;
  __syncthreads();
  if (t == 0) flag[0] = (s[0] + s[1] + s[2] + s[3] > 200) ? 1 : 0;
  for (int i = t; i < NN; i += 256) deg[i] = 0;
}

// ---------- normalize all float inputs into one fp32 region ----------
__global__ void convert_kernel(CvtSrc srcs, float* __restrict__ dst,
                               const int* __restrict__ flag) {
  int f = flag[0];
  for (int i = blockIdx.x * blockDim.x + threadIdx.x; i < TOTAL_F;
       i += gridDim.x * blockDim.x) {
    int tt = 0;
    while (i >= kPrefix[tt + 1]) ++tt;
    int off = i - kPrefix[tt];
    float v;
    if (f) v = ((const float*)srcs.p[tt])[off];
    else   v = b2f(((bfp)srcs.p[tt])[off]);
    dst[i] = v;
  }
}

// ---------- router scores: one wave per row, fp64 accumulate (rank stability) ----
__global__ void scores_kernel(const float* __restrict__ nf, const float* __restrict__ ef,
                              const float* __restrict__ wrn, const float* __restrict__ wre,
                              float* __restrict__ ns, float* __restrict__ es) {
  int gid = blockIdx.x * blockDim.x + threadIdx.x;
  int wid = gid >> 6, lane = gid & 63;
  if (wid >= NN + NE) return;
  const float* row; const float* w; float* out;
  if (wid < NN) { row = nf + (size_t)wid * D;        w = wrn; out = ns + wid; }
  else          { int r = wid - NN; row = ef + (size_t)r * D; w = wre; out = es + r; }
  double p = (double)row[lane] * (double)w[lane]
           + (double)row[lane + 64] * (double)w[lane + 64];
  #pragma unroll
  for (int m = 32; m >= 1; m >>= 1) p += __shfl_xor(p, m);
  if (lane == 0) *out = (float)p;
}

// ---------- exact top-k via stable rank, WAVE-PARALLEL (one wave per element) -----
// round-3 post-mortem: serial 4096-iter per-thread loop was 105 us at 0.7% occ.
__global__ void node_mask_kernel(const float* __restrict__ ns, int* __restrict__ node_mask) {
  __shared__ float s[NN];
  int t = threadIdx.x;
  for (int i = t; i < NN; i += 256) s[i] = ns[i];
  __syncthreads();
  int wid = t >> 6, lane = t & 63;
  int i = blockIdx.x * 4 + wid;          // grid = NN/4 blocks
  float si = s[i];
  int rank = 0;
  for (int j = lane; j < NN; j += 64) {  // 32 iters, LDS stride-1 (2-way, free)
    float sj = s[j];
    rank += (sj > si) || (sj == si && j < i);
  }
  #pragma unroll
  for (int m = 32; m >= 1; m >>= 1) rank += __shfl_xor(rank, m);
  if (lane == 0) node_mask[i] = (rank < NODE_K) ? 1 : 0;
}

__global__ void edge_mask_kernel(const float* __restrict__ es, const int* __restrict__ src,
                                 const int* __restrict__ dst, const int* __restrict__ node_mask,
                                 int* __restrict__ edge_mask) {
  __shared__ float s[NE];
  int t = threadIdx.x;
  for (int i = t; i < NE; i += 256) s[i] = es[i];
  __syncthreads();
  int wid = t >> 6, lane = t & 63;
  int i = blockIdx.x * 4 + wid;          // grid = NE/4 blocks
  float si = s[i];
  int rank = 0;
  for (int j = lane; j < NE; j += 64) {  // 64 iters
    float sj = s[j];
    rank += (sj > si) || (sj == si && j < i);
  }
  #pragma unroll
  for (int m = 32; m >= 1; m >>= 1) rank += __shfl_xor(rank, m);
  if (lane == 0)
    edge_mask[i] = ((rank < EDGE_K) && node_mask[src[i]] && node_mask[dst[i]]) ? 1 : 0;
}

// ---------- incident-edge lists ----------
__global__ void build_lists_kernel(const int* __restrict__ src, const int* __restrict__ dst,
                                   int* __restrict__ deg, int* __restrict__ lists) {
  int e = blockIdx.x * blockDim.x + threadIdx.x;
  if (e >= NE) return;
  int s = src[e], d = dst[e];
  int p = atomicAdd(&deg[s], 1);
  if (p >= 0 && p < CAP) lists[s * CAP + p] = e;
  if (d != s) {
    p = atomicAdd(&deg[d], 1);
    if (p >= 0 && p < CAP) lists[d * CAP + p] = e;
  }
}

// ---------- prep: masked edge feats + endpoint node-feature sum ----------
__global__ void prep_kernel(const float* __restrict__ ef, const float* __restrict__ nf,
                            const int* __restrict__ src, const int* __restrict__ dst,
                            const int* __restrict__ edge_mask,
                            float* __restrict__ efm, float* __restrict__ nsum) {
  int idx = blockIdx.x * blockDim.x + threadIdx.x;  // NE*D exactly
  int e = idx >> 7, c = idx & 127;
  float m = edge_mask[e] ? 1.f : 0.f;
  efm[idx] = m * ef[idx];
  nsum[idx] = nf[src[e] * D + c] + nf[dst[e] * D + c];
}

// ---------- C[M,128] = act(A @ W (+Cin)(+bias)), fp32, 16 rows/block ----------
#define ROWS 16
__global__ __launch_bounds__(256) void gemm_kernel(
    const float* __restrict__ A, const float* __restrict__ W,
    const float* __restrict__ Cin, const float* __restrict__ bias,
    int act, float* __restrict__ C) {
  __shared__ float Wl[64 * D];   // 32 KB (half of W at a time)
  __shared__ float Al[ROWS * D]; // 8 KB
  int t = threadIdx.x;
  int row0 = blockIdx.x * ROWS;
  for (int i = t; i < ROWS * D; i += 256) Al[i] = A[row0 * D + i];
  int j = t & 127, rg = t >> 7;  // rg in {0,1}: 8 rows per thread
  float acc[8] = {0.f, 0.f, 0.f, 0.f, 0.f, 0.f, 0.f, 0.f};
  for (int half = 0; half < 2; ++half) {
    __syncthreads();
    for (int i = t; i < 64 * D; i += 256) Wl[i] = W[half * 64 * D + i];
    __syncthreads();
    for (int k = 0; k < 64; ++k) {
      float w = Wl[k * D + j];
      #pragma unroll
      for (int r = 0; r < 8; ++r) acc[r] += Al[(rg * 8 + r) * D + (half * 64 + k)] * w;
    }
  }
  #pragma unroll
  for (int r = 0; r < 8; ++r) {
    int row = row0 + rg * 8 + r;
    float res = acc[r];
    if (Cin) res += Cin[row * D + j];
    if (bias) res += bias[j];
    if (act == 1) {  // jax.nn.gelu default (tanh approximation)
      float u = res;
      float inner = 0.7978845608028654f * (u + 0.044715f * u * u * u);
      res = 0.5f * u * (1.f + tanhf(inner));
    }
    C[row * D + j] = res;
  }
}

// ---------- fused h = A1@W1 + A2@W2 (one launch instead of two) ----------
__global__ __launch_bounds__(256) void gemm2_kernel(
    const float* __restrict__ A1, const float* __restrict__ W1,
    const float* __restrict__ A2, const float* __restrict__ W2,
    float* __restrict__ C) {
  __shared__ float Wl[64 * D];       // 32 KB
  __shared__ float Al[2 * ROWS * D]; // 16 KB
  int t = threadIdx.x;
  int row0 = blockIdx.x * ROWS;
  for (int i = t; i < ROWS * D; i += 256) {
    Al[i] = A1[row0 * D + i];
    Al[ROWS * D + i] = A2[row0 * D + i];
  }
  int j = t & 127, rg = t >> 7;
  float acc[8] = {0.f, 0.f, 0.f, 0.f, 0.f, 0.f, 0.f, 0.f};
  for (int part = 0; part < 2; ++part) {
    const float* W = part ? W2 : W1;
    const float* Ab = Al + part * ROWS * D;
    for (int half = 0; half < 2; ++half) {
      __syncthreads();
      for (int i = t; i < 64 * D; i += 256) Wl[i] = W[half * 64 * D + i];
      __syncthreads();
      for (int k = 0; k < 64; ++k) {
        float w = Wl[k * D + j];
        #pragma unroll
        for (int r = 0; r < 8; ++r) acc[r] += Ab[(rg * 8 + r) * D + (half * 64 + k)] * w;
      }
    }
  }
  #pragma unroll
  for (int r = 0; r < 8; ++r) C[(row0 + rg * 8 + r) * D + j] = acc[r];
}

// ---------- fused q,k,v: blockIdx.y selects W (WQ/WK/WV contiguous) ----------
__global__ __launch_bounds__(256) void gemm_qkv_kernel(
    const float* __restrict__ A, const float* __restrict__ Wq0,
    float* __restrict__ qkv) {
  __shared__ float Wl[64 * D];
  __shared__ float Al[ROWS * D];
  int t = threadIdx.x;
  int row0 = blockIdx.x * ROWS;
  const float* W = Wq0 + (size_t)blockIdx.y * D * D;
  float* C = qkv + (size_t)blockIdx.y * NE * D;
  for (int i = t; i < ROWS * D; i += 256) Al[i] = A[row0 * D + i];
  int j = t & 127, rg = t >> 7;
  float acc[8] = {0.f, 0.f, 0.f, 0.f, 0.f, 0.f, 0.f, 0.f};
  for (int half = 0; half < 2; ++half) {
    __syncthreads();
    for (int i = t; i < 64 * D; i += 256) Wl[i] = W[half * 64 * D + i];
    __syncthreads();
    for (int k = 0; k < 64; ++k) {
      float w = Wl[k * D + j];
      #pragma unroll
      for (int r = 0; r < 8; ++r) acc[r] += Al[(rg * 8 + r) * D + (half * 64 + k)] * w;
    }
  }
  #pragma unroll
  for (int r = 0; r < 8; ++r) C[(row0 + rg * 8 + r) * D + j] = acc[r];
}

// ---------- sparse edge attention: one block (128 thr) per query edge ----------
__global__ void attn_kernel(const float* __restrict__ q, const float* __restrict__ k,
                            const float* __restrict__ v, const int* __restrict__ src,
                            const int* __restrict__ dst, const int* __restrict__ deg,
                            const int* __restrict__ lists, float* __restrict__ ao) {
  int e = blockIdx.x;
  int j = threadIdx.x;  // head = j/32, d = j%32 (shfl_xor<32 stays in-head)
  float qj = q[e * D + j];
  int sn = src[e], dn = dst[e];
  float m = -1e30f, l = 0.f, acc = 0.f;
  const float scale = 0.17677669529663687f;  // 1/sqrt(32)
  int degA = max(0, min(deg[sn], CAP));
  for (int i = 0; i < degA; ++i) {
    int f = lists[sn * CAP + i];
    float p = qj * k[f * D + j];
    p += __shfl_xor(p, 16); p += __shfl_xor(p, 8); p += __shfl_xor(p, 4);
    p += __shfl_xor(p, 2);  p += __shfl_xor(p, 1);
    float s = p * scale;
    float vj = v[f * D + j];
    float mn = fmaxf(m, s);
    float corr = expf(m - mn);
    float w = expf(s - mn);
    l = l * corr + w;
    acc = acc * corr + w * vj;
    m = mn;
  }
  if (dn != sn) {
    int degB = max(0, min(deg[dn], CAP));
    for (int i = 0; i < degB; ++i) {
      int f = lists[dn * CAP + i];
      if (src[f] == sn || dst[f] == sn) continue;  // already in list A
      float p = qj * k[f * D + j];
      p += __shfl_xor(p, 16); p += __shfl_xor(p, 8); p += __shfl_xor(p, 4);
      p += __shfl_xor(p, 2);  p += __shfl_xor(p, 1);
      float s = p * scale;
      float vj = v[f * D + j];
      float mn = fmaxf(m, s);
      float corr = expf(m - mn);
      float w = expf(s - mn);
      l = l * corr + w;
      acc = acc * corr + w * vj;
      m = mn;
    }
  }
  ao[e * D + j] = acc / fmaxf(l, 1e-37f);
}

// ---------- logits: X[E,128] @ W2[128,16] + b2 -> out (dtype per flag) ----------
__global__ __launch_bounds__(256) void logits_kernel(
    const float* __restrict__ X, const float* __restrict__ W2,
    const float* __restrict__ b2v, const int* __restrict__ flag,
    void* __restrict__ out) {
  __shared__ float Xl[16 * D];
  __shared__ float W2l[D * 16];
  int t = threadIdx.x;
  int row0 = blockIdx.x * 16;
  for (int i = t; i < 16 * D; i += 256) Xl[i] = X[row0 * D + i];
  for (int i = t; i < D * 16; i += 256) W2l[i] = W2[i];
  __syncthreads();
  int j = t & 15, r = t >> 4;
  float acc = 0.f;
  for (int kk = 0; kk < D; ++kk) acc += Xl[r * D + kk] * W2l[kk * 16 + j];
  acc += b2v[j];
  int idx = (row0 + r) * 16 + j;
  if (flag[0]) ((float*)out)[idx] = acc;
  else ((__hip_bfloat16*)out)[idx] = __float2bfloat16(acc);
}

extern "C" void kernel_launch(void* const* d_in, const int* in_sizes, int n_in,
                              void* d_out, int out_size, void* d_ws, size_t ws_size,
                              hipStream_t stream) {
  const int* eidx = (const int*)d_in[2];
  const int* src = eidx;
  const int* dst = eidx + NE;

  size_t off = 0;
  char* base = (char*)d_ws;
  auto alloc = [&](size_t nbytes) -> void* {
    void* p = base + off;
    off += (nbytes + 255) & ~(size_t)255;
    return p;
  };
  int* flag        = (int*)alloc(256);
  float* F         = (float*)alloc((size_t)TOTAL_F * sizeof(float));
  float* ns        = (float*)alloc(NN * sizeof(float));
  float* es        = (float*)alloc(NE * sizeof(float));
  int* node_mask   = (int*)alloc(NN * sizeof(int));
  int* edge_mask   = (int*)alloc(NE * sizeof(int));
  int* deg         = (int*)alloc(NN * sizeof(int));
  int* lists       = (int*)alloc((size_t)NN * CAP * sizeof(int));
  float* efm       = (float*)alloc((size_t)NE * D * sizeof(float));
  float* nsum      = (float*)alloc((size_t)NE * D * sizeof(float));
  float* hbuf      = (float*)alloc((size_t)NE * D * sizeof(float));
  float* qkv       = (float*)alloc((size_t)3 * NE * D * sizeof(float));
  float* ao        = (float*)alloc((size_t)NE * D * sizeof(float));
  float* ob = efm;   // reuse (dead after h)
  float* xb = nsum;  // reuse (dead after h)
  float* qb = qkv, *kb = qkv + NE * D, *vb = qkv + 2 * NE * D;

  const float* NF  = F + 0;
  const float* EF  = F + 262144;
  const float* WRN = F + 786432;
  const float* WRE = F + 786560;
  const float* WE  = F + 786688;
  const float* WNp = F + 803072;
  const float* WQ  = F + 819456;   // WQ,WK,WV contiguous
  const float* WO  = F + 868608;
  const float* W1  = F + 884992;
  const float* B1  = F + 901376;
  const float* W2P = F + 901504;
  const float* B2P = F + 903552;

  CvtSrc srcs;
  srcs.p[0]  = d_in[0];  srcs.p[1]  = d_in[1];  srcs.p[2]  = d_in[3];
  srcs.p[3]  = d_in[4];  srcs.p[4]  = d_in[5];  srcs.p[5]  = d_in[6];
  srcs.p[6]  = d_in[7];  srcs.p[7]  = d_in[8];  srcs.p[8]  = d_in[9];
  srcs.p[9]  = d_in[10]; srcs.p[10] = d_in[11]; srcs.p[11] = d_in[12];
  srcs.p[12] = d_in[13]; srcs.p[13] = d_in[14];

  detect_kernel<<<1, 256, 0, stream>>>((const unsigned short*)d_in[0], flag, deg);
  convert_kernel<<<1024, 256, 0, stream>>>(srcs, F, flag);
  scores_kernel<<<(NN + NE) * 64 / 256, 256, 0, stream>>>(NF, EF, WRN, WRE, ns, es);
  node_mask_kernel<<<NN / 4, 256, 0, stream>>>(ns, node_mask);
  edge_mask_kernel<<<NE / 4, 256, 0, stream>>>(es, src, dst, node_mask, edge_mask);
  build_lists_kernel<<<NE / 256, 256, 0, stream>>>(src, dst, deg, lists);
  prep_kernel<<<(NE * D) / 256, 256, 0, stream>>>(EF, NF, src, dst, edge_mask, efm, nsum);
  gemm2_kernel<<<NE / ROWS, 256, 0, stream>>>(efm, WE, nsum, WNp, hbuf);
  gemm_qkv_kernel<<<dim3(NE / ROWS, 3), 256, 0, stream>>>(hbuf, WQ, qkv);
  attn_kernel<<<NE, 128, 0, stream>>>(qb, kb, vb, src, dst, deg, lists, ao);
  gemm_kernel<<<NE / ROWS, 256, 0, stream>>>(ao, WO, nullptr, nullptr, 0, ob);
  gemm_kernel<<<NE / ROWS, 256, 0, stream>>>(ob, W1, nullptr, B1, 1, xb);
  logits_kernel<<<NE / 16, 256, 0, stream>>>(xb, W2P, B2P, flag, d_out);
}